// Round 10
// baseline (311.672 us; speedup 1.0000x reference)
//
#include <hip/hip_runtime.h>
#include <stdint.h>

// Problem constants (fixed by the harness)
#define DM    1024          // d_model
#define NH    16            // heads
#define DKH   64            // head dim
#define SEQ   2048
#define NB    4
#define MROWS (NB * SEQ)    // 8192 rows for all GEMMs

typedef __attribute__((ext_vector_type(4))) float f32x4;
typedef __attribute__((ext_vector_type(8))) short s16x8;           // 8 x bf16 (4 VGPR) MFMA frag
typedef __attribute__((ext_vector_type(4))) unsigned short u16x4;
typedef __attribute__((ext_vector_type(8))) unsigned short u16x8;

__device__ __forceinline__ unsigned short f2bf(float f) {
  union { float f; uint32_t u; } v; v.f = f;
  uint32_t r = v.u + 0x7fffu + ((v.u >> 16) & 1u);   // RNE
  return (unsigned short)(r >> 16);
}

// async global->LDS, 16B per lane. LDS dest is wave-uniform base (+lane*16 by HW).
__device__ __forceinline__ void gload16(const void* g, void* l) {
  __builtin_amdgcn_global_load_lds(
      (__attribute__((address_space(1))) void*)(uintptr_t)g,
      (__attribute__((address_space(3))) void*)(uint32_t)(uintptr_t)l,
      16, 0, 0);
}

__device__ __forceinline__ float exp2fast(float x) {
#if __has_builtin(__builtin_amdgcn_exp2f)
  return __builtin_amdgcn_exp2f(x);
#else
  return exp2f(x);
#endif
}

// hardware packed f32->bf16 (T12): D[15:0]=bf16(a), D[31:16]=bf16(b)
__device__ __forceinline__ unsigned int cvtpk(float a, float b) {
  unsigned int r;
  asm("v_cvt_pk_bf16_f32 %0, %1, %2" : "=v"(r) : "v"(a), "v"(b));
  return r;
}

__device__ __forceinline__ float bperm(float v, int srclane) {
  union { float f; int i; } u; u.f = v;
  u.i = __builtin_amdgcn_ds_bpermute(srclane << 2, u.i);
  return u.f;
}

// ---------------------------------------------------------------- fp32 -> bf16 (weights only)
__device__ __forceinline__ void cvt8(const float* in, unsigned short* out, int i) {
  const f32x4* p = (const f32x4*)(in + i);
  f32x4 a = p[0], b = p[1];
  u16x8 r;
#pragma unroll
  for (int j = 0; j < 4; ++j) { r[j] = f2bf(a[j]); r[4 + j] = f2bf(b[j]); }
  *(u16x8*)(out + i) = r;
}

// 4 weight matrices, 1M elems each: 512 blocks per tensor
__global__ __launch_bounds__(256) void cvt4_kernel(const float* __restrict__ a,
                                                   const float* __restrict__ b,
                                                   const float* __restrict__ c,
                                                   const float* __restrict__ d,
                                                   unsigned short* __restrict__ oa,
                                                   unsigned short* __restrict__ ob,
                                                   unsigned short* __restrict__ oc,
                                                   unsigned short* __restrict__ od) {
  const int seg = blockIdx.x >> 9;
  const int blk = blockIdx.x & 511;
  const float* in = (seg == 0) ? a : (seg == 1) ? b : (seg == 2) ? c : d;
  unsigned short* out = (seg == 0) ? oa : (seg == 1) ? ob : (seg == 2) ? oc : od;
  cvt8(in, out, (blk * 256 + threadIdx.x) * 8);
}

// ---------------------------------------------------------------- GEMM  C = A * B^T + bias
// R7-proven structure (verbatim): 128x128 tile, BK=64, 4 waves (2x2), double-buffered
// LDS, XOR-swizzled, global_load_lds width 16 for B (and A when bf16), __syncthreads()
// drain each K-step. No counted vmcnt, no setprio, no sched_barrier (m141/m190 lessons).
// AFP32=1: A fp32 reg-staged (T14 issue-early/write-late) -> same swizzled LDS bytes.
// MODE 0: bf16 out, (B,h,S,dk), scaled by oscale
// MODE 1: bf16 out, (B,h,dk,S') pi-permuted per 32-kv block (PV B-frag contiguous)
// MODE 2: f32 out, row-major [M][N]
template <int MODE, int AFP32>
__global__ __launch_bounds__(256) void gemm_bt(const void* __restrict__ Ap,
                                               const unsigned short* __restrict__ Bw,
                                               const float* __restrict__ bias,
                                               void* __restrict__ out,
                                               float oscale) {
  __shared__ char smem[65536];   // 2 x (As 16K + Bs 16K)

  int bid = (int)(blockIdx.y * 8 + blockIdx.x);
  bid = (bid & 7) * 64 + (bid >> 3);          // XCD swizzle (512 % 8 == 0, bijective)
  const int tcol = (bid & 7) * 128;
  const int trow = (bid >> 3) * 128;

  const int lane = threadIdx.x & 63;
  const int w    = threadIdx.x >> 6;
  const int wm = w >> 1, wn = w & 1;
  const int l15 = lane & 15, l4 = lane >> 4;

  const float* Af = (const float*)Ap;
  const unsigned short* Ah = (const unsigned short*)Ap;

  const int srow = w * 8 + (lane >> 3);            // row within each 32-row group
  const int sc   = ((lane & 7) ^ (lane >> 3)) * 8; // pre-swizzled source k-offset (elems)
  const int ldst = (lane & 7) * 16;                // linear LDS byte slot within row

  f32x4 acc[4][4] = {};
  f32x4 areg[4][2];   // in-flight A fp32 (AFP32 path)

  auto aload = [&](int k0) {   // issue-early: 8 x f32x4 global loads
#pragma unroll
    for (int i = 0; i < 4; ++i) {
      const float* p = Af + (size_t)(trow + i * 32 + srow) * DM + k0 + sc;
      areg[i][0] = *(const f32x4*)p;
      areg[i][1] = *(const f32x4*)(p + 4);
    }
  };
  auto awrite = [&](int buf) { // write-late: cvt_pk + ds_write_b128 (same bytes as gload path)
    char* As = smem + buf * 32768;
#pragma unroll
    for (int i = 0; i < 4; ++i) {
      union { unsigned int u[4]; s16x8 v; } pu;
      pu.u[0] = cvtpk(areg[i][0][0], areg[i][0][1]);
      pu.u[1] = cvtpk(areg[i][0][2], areg[i][0][3]);
      pu.u[2] = cvtpk(areg[i][1][0], areg[i][1][1]);
      pu.u[3] = cvtpk(areg[i][1][2], areg[i][1][3]);
      *(s16x8*)(As + (i * 32 + srow) * 128 + ldst) = pu.v;
    }
  };
  auto astage = [&](int buf, int k0) {  // bf16 A via global_load_lds
    char* As = smem + buf * 32768;
#pragma unroll
    for (int i = 0; i < 4; ++i)
      gload16(Ah + (size_t)(trow + i * 32 + srow) * DM + k0 + sc, As + i * 4096 + w * 1024);
  };
  auto bstage = [&](int buf, int k0) {
    char* Bs = smem + buf * 32768 + 16384;
#pragma unroll
    for (int i = 0; i < 4; ++i)
      gload16(Bw + (size_t)(tcol + i * 32 + srow) * DM + k0 + sc, Bs + i * 4096 + w * 1024);
  };
  auto compute = [&](int buf) {
    char* As = smem + buf * 32768;
    char* Bs = As + 16384;
#pragma unroll
    for (int ks = 0; ks < 2; ++ks) {
      s16x8 af[4], bf[4];
#pragma unroll
      for (int x = 0; x < 4; ++x) {
        const int ra = wm * 64 + x * 16 + l15;
        const int rb = wn * 64 + x * 16 + l15;
        const int kb = ks * 4 + l4;
        af[x] = *(const s16x8*)(As + ra * 128 + ((kb ^ (ra & 7)) << 4));
        bf[x] = *(const s16x8*)(Bs + rb * 128 + ((kb ^ (rb & 7)) << 4));
      }
#pragma unroll
      for (int mi = 0; mi < 4; ++mi)
#pragma unroll
        for (int ni = 0; ni < 4; ++ni)
          acc[mi][ni] = __builtin_amdgcn_mfma_f32_16x16x32_bf16(af[mi], bf[ni], acc[mi][ni], 0, 0, 0);
    }
  };

  // prologue
  if (AFP32) aload(0); else astage(0, 0);
  bstage(0, 0);
  if (AFP32) awrite(0);
  __syncthreads();
  int cur = 0;

  for (int k0 = 0; k0 < DM; k0 += 64) {
    const bool more = (k0 + 64 < DM);
    if (more) {
      if (AFP32) aload(k0 + 64); else astage(cur ^ 1, k0 + 64);
      bstage(cur ^ 1, k0 + 64);
    }
    compute(cur);
    if (more && AFP32) awrite(cur ^ 1);
    __syncthreads();
    cur ^= 1;
  }

  // epilogue.  C/D layout: row = l4*4 + j, col = l15
#pragma unroll
  for (int ni = 0; ni < 4; ++ni) {
    const int n  = tcol + wn * 64 + ni * 16 + l15;
    const float bv = bias[n];
#pragma unroll
    for (int mi = 0; mi < 4; ++mi) {
      const int m0 = trow + wm * 64 + mi * 16 + l4 * 4;
      if (MODE == 2) {
        float* o = (float*)out;
#pragma unroll
        for (int j = 0; j < 4; ++j)
          o[(size_t)(m0 + j) * DM + n] = acc[mi][ni][j] + bv;
      } else if (MODE == 0) {
        unsigned short* o = (unsigned short*)out;
        const int bb = m0 >> 11, h = n >> 6, dk = n & 63;
#pragma unroll
        for (int j = 0; j < 4; ++j) {
          const int s = (m0 + j) & 2047;
          o[(((size_t)bb * NH + h) * SEQ + s) * DKH + dk] = f2bf((acc[mi][ni][j] + bv) * oscale);
        }
      } else {  // MODE 1: (B,h,dk,S'), pi-permuted col, 4 consecutive -> packed 8B store
        unsigned short* o = (unsigned short*)out;
        const int bb = m0 >> 11, h = n >> 6, dk = n & 63, s = m0 & 2047;
        const int u = s & 31;   // u&3 == 0 (s is 4-aligned)
        const int s2 = (s & ~31) | ((u & 12) << 1) | ((u & 16) >> 2);
        u16x4 pk;
#pragma unroll
        for (int j = 0; j < 4; ++j) pk[j] = f2bf(acc[mi][ni][j] + bv);
        *(u16x4*)(o + (((size_t)bb * NH + h) * DKH + dk) * SEQ + s2) = pk;
      }
    }
  }
}

// ---------------------------------------------------------------- flash attention
// R7 structure (256 threads, 4 waves x 64 q-rows, q-tile 256, grid 512) + T15 score
// double-pipeline (R4-proven): named saA/saB; K staged TWO tiles ahead, V one ahead;
// per body: stage -> qkt(t+1 -> other sa) -> smpv(t). qkt's 32 independent MFMAs
// overlap smpv's 64 exp2 + 32 cvtpk on the VALU. All buffer overwrites are
// barrier-separated from their last readers (__syncthreads drains vmcnt -> async
// stages visible). VGPR +64 is free at the grid-capped 2 waves/SIMD.
__global__ __launch_bounds__(256, 2) void attn_kernel(const unsigned short* __restrict__ qh,
                                                      const unsigned short* __restrict__ kh,
                                                      const unsigned short* __restrict__ vth,
                                                      unsigned short* __restrict__ ao) {
  __shared__ char smem[32768];   // Ks0 @0, Ks1 @8192, Vs0 @16384, Vs1 @24576

  int bid = (int)blockIdx.x;              // 512 blocks
  bid = (bid & 7) * 64 + (bid >> 3);      // XCD swizzle: 8 heads per XCD -> KV L2-resident
  const int bh = bid >> 3;                // 0..63
  const int q0 = (bid & 7) * 256;         // q tile base

  const int lane = threadIdx.x & 63;
  const int w    = threadIdx.x >> 6;
  const int l15 = lane & 15, l4 = lane >> 4;

  const int qrow = q0 + w * 64;
  const unsigned short* qbase = qh + ((size_t)bh * SEQ + qrow) * DKH;

  s16x8 qf[4][2];
#pragma unroll
  for (int ni = 0; ni < 4; ++ni)
#pragma unroll
    for (int ks = 0; ks < 2; ++ks)
      qf[ni][ks] = *(const s16x8*)(qbase + (ni * 16 + l15) * DKH + ks * 32 + l4 * 8);

  // loop-invariant LDS fragment byte offsets (relative to buffer base)
  int koff[2][4], voff[2][4];
#pragma unroll
  for (int ks = 0; ks < 2; ++ks)
#pragma unroll
    for (int mi = 0; mi < 4; ++mi) {
      const int r = mi * 16 + l15;
      koff[ks][mi] = r * 128 + (((ks * 4 + l4) ^ (r & 7)) << 4);
    }
#pragma unroll
  for (int m = 0; m < 2; ++m)
#pragma unroll
    for (int nd = 0; nd < 4; ++nd) {
      const int r = nd * 16 + l15;
      voff[m][nd] = r * 128 + (((m * 4 + l4) ^ (r & 7)) << 4);
    }

  f32x4 o[4][4] = {};
  f32x4 lsum[4] = {};   // P column-sums via ones-MFMA (valid at lanes l15==0)

  // ones-column B fragment: B[k][n] = (n==0) ? 1 : 0
  s16x8 onesB = (s16x8)0;
  if (l15 == 0) {
#pragma unroll
    for (int j = 0; j < 8; ++j) onesB[j] = (short)0x3F80;
  }

  const unsigned short* kbase = kh  + (size_t)bh * SEQ * DKH;
  const unsigned short* vbase = vth + (size_t)bh * DKH * SEQ;

  auto stageK = [&](int buf, int kv0) {
    char* Ks = smem + buf * 8192;
#pragma unroll
    for (int i = 0; i < 2; ++i) {
      const int row = i * 32 + w * 8 + (lane >> 3);
      const int sc  = ((lane & 7) ^ (row & 7)) << 3;
      gload16(kbase + (size_t)(kv0 + row) * DKH + sc, Ks + i * 4096 + w * 1024);
    }
  };
  auto stageV = [&](int buf, int kv0) {
    char* Vs = smem + 16384 + buf * 8192;
#pragma unroll
    for (int i = 0; i < 2; ++i) {
      const int row = i * 32 + w * 8 + (lane >> 3);   // dk row
      const int sc  = ((lane & 7) ^ (row & 7)) << 3;
      gload16(vbase + (size_t)row * SEQ + kv0 + sc, Vs + i * 4096 + w * 1024);
    }
  };

  f32x4 saA[4][4], saB[4][4];   // named 2-deep score pipeline (rule #20: no runtime index)

  auto qkt = [&](const char* Ks, f32x4 (&sa)[4][4]) {
#pragma unroll
    for (int mi = 0; mi < 4; ++mi)
#pragma unroll
      for (int ni = 0; ni < 4; ++ni) sa[mi][ni] = (f32x4)0.f;
    __builtin_amdgcn_s_setprio(1);
#pragma unroll
    for (int ks = 0; ks < 2; ++ks) {
      s16x8 kf[4];
#pragma unroll
      for (int mi = 0; mi < 4; ++mi) kf[mi] = *(const s16x8*)(Ks + koff[ks][mi]);
#pragma unroll
      for (int mi = 0; mi < 4; ++mi)
#pragma unroll
        for (int ni = 0; ni < 4; ++ni)
          sa[mi][ni] = __builtin_amdgcn_mfma_f32_16x16x32_bf16(kf[mi], qf[ni][ks], sa[mi][ni], 0, 0, 0);
    }
    __builtin_amdgcn_s_setprio(0);
  };

  auto smpv = [&](const char* Vs, f32x4 (&sa)[4][4]) {
    // P = exp2(S) in place (Q pre-scaled by log2(e)/8; no max needed, |S| <= ~14.4)
#pragma unroll
    for (int mi = 0; mi < 4; ++mi)
#pragma unroll
      for (int ni = 0; ni < 4; ++ni)
#pragma unroll
        for (int j = 0; j < 4; ++j)
          sa[mi][ni][j] = exp2fast(sa[mi][ni][j]);

    // PV + ones-sum: O[q][dk] += P*V ; lsum += P*ones  (K=32 MFMA, pi-permuted k)
    __builtin_amdgcn_s_setprio(1);
#pragma unroll
    for (int m = 0; m < 2; ++m) {
      s16x8 pa[4];
#pragma unroll
      for (int ni = 0; ni < 4; ++ni) {
        union { unsigned int u[4]; s16x8 v; } pu;
        pu.u[0] = cvtpk(sa[2 * m][ni][0],     sa[2 * m][ni][1]);
        pu.u[1] = cvtpk(sa[2 * m][ni][2],     sa[2 * m][ni][3]);
        pu.u[2] = cvtpk(sa[2 * m + 1][ni][0], sa[2 * m + 1][ni][1]);
        pu.u[3] = cvtpk(sa[2 * m + 1][ni][2], sa[2 * m + 1][ni][3]);
        pa[ni] = pu.v;
      }
#pragma unroll
      for (int ni = 0; ni < 4; ++ni)
        lsum[ni] = __builtin_amdgcn_mfma_f32_16x16x32_bf16(pa[ni], onesB, lsum[ni], 0, 0, 0);
#pragma unroll
      for (int nd = 0; nd < 4; ++nd) {
        const s16x8 vbf = *(const s16x8*)(Vs + voff[m][nd]);
#pragma unroll
        for (int ni = 0; ni < 4; ++ni)
          o[ni][nd] = __builtin_amdgcn_mfma_f32_16x16x32_bf16(pa[ni], vbf, o[ni][nd], 0, 0, 0);
      }
    }
    __builtin_amdgcn_s_setprio(0);
  };

  // ---- T15 pipeline prologue: K(0),V(0),K(1) staged; scores(0) -> saA
  stageK(0, 0); stageV(0, 0); stageK(1, 64);
  __syncthreads();
  qkt(smem, saA);
  __syncthreads();   // all waves done reading Ks0 before body A overwrites it with K(2)

  for (int t = 0; t < 32; t += 2) {
    const int kv0 = t * 64;
    // body A (tile t, even): prefetch K(t+2)->Ks0, V(t+1)->Vs1; scores(t+1)->saB; PV(t)
    if (t + 2 < 32) stageK(0, kv0 + 128);
    stageV(1, kv0 + 64);
    qkt(smem + 8192, saB);             // Ks1 = K(t+1), staged 2 bodies ago, barrier-visible
    smpv(smem + 16384, saA);           // Vs0 = V(t)
    __syncthreads();
    // body B (tile t+1): prefetch K(t+3)->Ks1, V(t+2)->Vs0; scores(t+2)->saA; PV(t+1)
    if (t + 3 < 32) stageK(1, kv0 + 192);
    if (t + 2 < 32) { stageV(0, kv0 + 128); qkt(smem, saA); }
    smpv(smem + 16384 + 8192, saB);    // Vs1 = V(t+1)
    __syncthreads();
  }

  // normalize (broadcast lsum from col-0 lanes) + store to (B,S,h*dk)
  const int bb = bh >> 4, h = bh & 15;
#pragma unroll
  for (int ni = 0; ni < 4; ++ni) {
#pragma unroll
    for (int j = 0; j < 4; ++j) {
      const float inv = 1.0f / bperm(lsum[ni][j], lane & 48);
      const int s = qrow + ni * 16 + l4 * 4 + j;
#pragma unroll
      for (int nd = 0; nd < 4; ++nd) {
        const int col = h * 64 + nd * 16 + l15;
        ao[((size_t)bb * SEQ + s) * DM + col] = f2bf(o[ni][nd][j] * inv);
      }
    }
  }
}

// ---------------------------------------------------------------- launch
extern "C" void kernel_launch(void* const* d_in, const int* in_sizes, int n_in,
                              void* d_out, int out_size, void* d_ws, size_t ws_size,
                              hipStream_t stream) {
  const float* Q  = (const float*)d_in[0];
  const float* K  = (const float*)d_in[1];
  const float* V  = (const float*)d_in[2];
  const float* Wq = (const float*)d_in[3];
  const float* bq = (const float*)d_in[4];
  const float* Wk = (const float*)d_in[5];
  const float* bk = (const float*)d_in[6];
  const float* Wv = (const float*)d_in[7];
  const float* bv = (const float*)d_in[8];
  const float* Wo = (const float*)d_in[9];
  const float* bo = (const float*)d_in[10];
  float* out = (float*)d_out;

  char* ws = (char*)d_ws;
  const size_t MB = 1024 * 1024;
  unsigned short* Wqb = (unsigned short*)(ws + 0 * MB);     // 2 MB each
  unsigned short* Wkb = (unsigned short*)(ws + 2 * MB);
  unsigned short* Wvb = (unsigned short*)(ws + 4 * MB);
  unsigned short* Wob = (unsigned short*)(ws + 6 * MB);
  unsigned short* qhd = (unsigned short*)(ws + 8 * MB);     // (B,h,S,dk), pre-scaled by log2e/8
  unsigned short* khd = (unsigned short*)(ws + 24 * MB);    // (B,h,S,dk)
  unsigned short* vtd = (unsigned short*)(ws + 40 * MB);    // (B,h,dk,S') pi-permuted
  unsigned short* aod = (unsigned short*)(ws + 56 * MB);    // (B,S,DM)

  const float QSCALE = 0.18033688011112042f;  // log2(e) / 8 folded into Q projection

  cvt4_kernel<<<dim3(4 * 512), 256, 0, stream>>>(Wq, Wk, Wv, Wo, Wqb, Wkb, Wvb, Wob);

  dim3 gg(DM / 128, MROWS / 128);   // (8, 64)
  gemm_bt<0, 1><<<gg, 256, 0, stream>>>(Q, Wqb, bq, qhd, QSCALE);
  gemm_bt<0, 1><<<gg, 256, 0, stream>>>(K, Wkb, bk, khd, 1.0f);
  gemm_bt<1, 1><<<gg, 256, 0, stream>>>(V, Wvb, bv, vtd, 1.0f);

  attn_kernel<<<dim3(512), 256, 0, stream>>>(qhd, khd, vtd, aod);

  gemm_bt<2, 0><<<gg, 256, 0, stream>>>(aod, Wob, bo, out, 1.0f);
}

// Round 11
// 161.153 us; speedup vs baseline: 1.9340x; 1.9340x over previous
//
#include <hip/hip_runtime.h>
#include <stdint.h>

// Problem constants (fixed by the harness)
#define DM    1024          // d_model
#define NH    16            // heads
#define DKH   64            // head dim
#define SEQ   2048
#define NB    4
#define MROWS (NB * SEQ)    // 8192 rows for all GEMMs

typedef __attribute__((ext_vector_type(4))) float f32x4;
typedef __attribute__((ext_vector_type(8))) short s16x8;           // 8 x bf16 (4 VGPR) MFMA frag
typedef __attribute__((ext_vector_type(4))) unsigned short u16x4;
typedef __attribute__((ext_vector_type(8))) unsigned short u16x8;

__device__ __forceinline__ unsigned short f2bf(float f) {
  union { float f; uint32_t u; } v; v.f = f;
  uint32_t r = v.u + 0x7fffu + ((v.u >> 16) & 1u);   // RNE
  return (unsigned short)(r >> 16);
}

// async global->LDS, 16B per lane. LDS dest is wave-uniform base (+lane*16 by HW).
__device__ __forceinline__ void gload16(const void* g, void* l) {
  __builtin_amdgcn_global_load_lds(
      (__attribute__((address_space(1))) void*)(uintptr_t)g,
      (__attribute__((address_space(3))) void*)(uint32_t)(uintptr_t)l,
      16, 0, 0);
}

__device__ __forceinline__ float exp2fast(float x) {
#if __has_builtin(__builtin_amdgcn_exp2f)
  return __builtin_amdgcn_exp2f(x);
#else
  return exp2f(x);
#endif
}

// hardware packed f32->bf16 (T12): D[15:0]=bf16(a), D[31:16]=bf16(b)
__device__ __forceinline__ unsigned int cvtpk(float a, float b) {
  unsigned int r;
  asm("v_cvt_pk_bf16_f32 %0, %1, %2" : "=v"(r) : "v"(a), "v"(b));
  return r;
}

__device__ __forceinline__ float bperm(float v, int srclane) {
  union { float f; int i; } u; u.f = v;
  u.i = __builtin_amdgcn_ds_bpermute(srclane << 2, u.i);
  return u.f;
}

// ---------------------------------------------------------------- fp32 -> bf16 (weights only)
__device__ __forceinline__ void cvt8(const float* in, unsigned short* out, int i) {
  const f32x4* p = (const f32x4*)(in + i);
  f32x4 a = p[0], b = p[1];
  u16x8 r;
#pragma unroll
  for (int j = 0; j < 4; ++j) { r[j] = f2bf(a[j]); r[4 + j] = f2bf(b[j]); }
  *(u16x8*)(out + i) = r;
}

// 4 weight matrices, 1M elems each: 512 blocks per tensor
__global__ __launch_bounds__(256) void cvt4_kernel(const float* __restrict__ a,
                                                   const float* __restrict__ b,
                                                   const float* __restrict__ c,
                                                   const float* __restrict__ d,
                                                   unsigned short* __restrict__ oa,
                                                   unsigned short* __restrict__ ob,
                                                   unsigned short* __restrict__ oc,
                                                   unsigned short* __restrict__ od) {
  const int seg = blockIdx.x >> 9;
  const int blk = blockIdx.x & 511;
  const float* in = (seg == 0) ? a : (seg == 1) ? b : (seg == 2) ? c : d;
  unsigned short* out = (seg == 0) ? oa : (seg == 1) ? ob : (seg == 2) ? oc : od;
  cvt8(in, out, (blk * 256 + threadIdx.x) * 8);
}

// ---------------------------------------------------------------- fused QKV GEMM (fp32 A)
// R7-proven dataflow and sync VERBATIM (plain __syncthreads each K-step; no counted
// vmcnt, no setprio, no sched_barrier — m141/m190/R8 lessons). 128x128 tile, BK=64,
// 4 waves (2x2), double-buffered XOR-swizzled LDS, global_load_lds width 16 for B.
// A fp32 reg-staged (T14 issue-early/write-late) -> same swizzled LDS bytes as the
// gload path. z selects Q/K/V (fusion itself proven correctness-safe in R8).
// z<2: out (B,h,S,dk) scaled by oscale; z==2: (B,h,dk,S') pi-permuted per 32-kv block.
__global__ __launch_bounds__(256) void gemm_qkv(const float* __restrict__ Aq,
                                                const float* __restrict__ Ak,
                                                const float* __restrict__ Av,
                                                const unsigned short* __restrict__ Wq,
                                                const unsigned short* __restrict__ Wk,
                                                const unsigned short* __restrict__ Wv,
                                                const float* __restrict__ biq,
                                                const float* __restrict__ bik,
                                                const float* __restrict__ biv,
                                                unsigned short* __restrict__ oq,
                                                unsigned short* __restrict__ ok,
                                                unsigned short* __restrict__ ov,
                                                float qscale) {
  __shared__ char smem[65536];   // 2 x (As 16K + Bs 16K)

  const int z = blockIdx.z;
  const float* Af = (z == 0) ? Aq : (z == 1) ? Ak : Av;
  const unsigned short* Bw = (z == 0) ? Wq : (z == 1) ? Wk : Wv;
  const float* bias = (z == 0) ? biq : (z == 1) ? bik : biv;
  unsigned short* out = (z == 0) ? oq : (z == 1) ? ok : ov;
  const float oscale = (z == 0) ? qscale : 1.0f;

  int bid = (int)(blockIdx.y * 8 + blockIdx.x);
  bid = (bid & 7) * 64 + (bid >> 3);          // XCD swizzle (512 % 8 == 0, bijective)
  const int tcol = (bid & 7) * 128;
  const int trow = (bid >> 3) * 128;

  const int lane = threadIdx.x & 63;
  const int w    = threadIdx.x >> 6;
  const int wm = w >> 1, wn = w & 1;
  const int l15 = lane & 15, l4 = lane >> 4;

  const int srow = w * 8 + (lane >> 3);            // row within each 32-row group
  const int sc   = ((lane & 7) ^ (lane >> 3)) * 8; // pre-swizzled source k-offset (elems)
  const int ldst = (lane & 7) * 16;                // linear LDS byte slot within row

  f32x4 acc[4][4] = {};
  f32x4 areg[4][2];   // in-flight A fp32

  auto aload = [&](int k0) {   // issue-early: 8 x f32x4 global loads
#pragma unroll
    for (int i = 0; i < 4; ++i) {
      const float* p = Af + (size_t)(trow + i * 32 + srow) * DM + k0 + sc;
      areg[i][0] = *(const f32x4*)p;
      areg[i][1] = *(const f32x4*)(p + 4);
    }
  };
  auto awrite = [&](int buf) { // write-late: cvt_pk + ds_write_b128
    char* As = smem + buf * 32768;
#pragma unroll
    for (int i = 0; i < 4; ++i) {
      union { unsigned int u[4]; s16x8 v; } pu;
      pu.u[0] = cvtpk(areg[i][0][0], areg[i][0][1]);
      pu.u[1] = cvtpk(areg[i][0][2], areg[i][0][3]);
      pu.u[2] = cvtpk(areg[i][1][0], areg[i][1][1]);
      pu.u[3] = cvtpk(areg[i][1][2], areg[i][1][3]);
      *(s16x8*)(As + (i * 32 + srow) * 128 + ldst) = pu.v;
    }
  };
  auto bstage = [&](int buf, int k0) {
    char* Bs = smem + buf * 32768 + 16384;
#pragma unroll
    for (int i = 0; i < 4; ++i)
      gload16(Bw + (size_t)(tcol + i * 32 + srow) * DM + k0 + sc, Bs + i * 4096 + w * 1024);
  };
  auto compute = [&](int buf) {
    char* As = smem + buf * 32768;
    char* Bs = As + 16384;
#pragma unroll
    for (int ks = 0; ks < 2; ++ks) {
      s16x8 af[4], bf[4];
#pragma unroll
      for (int x = 0; x < 4; ++x) {
        const int ra = wm * 64 + x * 16 + l15;
        const int rb = wn * 64 + x * 16 + l15;
        const int kb = ks * 4 + l4;
        af[x] = *(const s16x8*)(As + ra * 128 + ((kb ^ (ra & 7)) << 4));
        bf[x] = *(const s16x8*)(Bs + rb * 128 + ((kb ^ (rb & 7)) << 4));
      }
#pragma unroll
      for (int mi = 0; mi < 4; ++mi)
#pragma unroll
        for (int ni = 0; ni < 4; ++ni)
          acc[mi][ni] = __builtin_amdgcn_mfma_f32_16x16x32_bf16(af[mi], bf[ni], acc[mi][ni], 0, 0, 0);
    }
  };

  // prologue
  aload(0);
  bstage(0, 0);
  awrite(0);
  __syncthreads();
  int cur = 0;

  for (int k0 = 0; k0 < DM; k0 += 64) {
    const bool more = (k0 + 64 < DM);
    if (more) {
      aload(k0 + 64);
      bstage(cur ^ 1, k0 + 64);
    }
    compute(cur);
    if (more) awrite(cur ^ 1);
    __syncthreads();
    cur ^= 1;
  }

  // epilogue.  C/D layout: row = l4*4 + j, col = l15
#pragma unroll
  for (int ni = 0; ni < 4; ++ni) {
    const int n  = tcol + wn * 64 + ni * 16 + l15;
    const float bv = bias[n];
#pragma unroll
    for (int mi = 0; mi < 4; ++mi) {
      const int m0 = trow + wm * 64 + mi * 16 + l4 * 4;
      const int bb = m0 >> 11, h = n >> 6, dk = n & 63;
      if (z != 2) {
#pragma unroll
        for (int j = 0; j < 4; ++j) {
          const int s = (m0 + j) & 2047;
          out[(((size_t)bb * NH + h) * SEQ + s) * DKH + dk] = f2bf((acc[mi][ni][j] + bv) * oscale);
        }
      } else {  // (B,h,dk,S'), pi-permuted col, 4 consecutive -> packed 8B store
        const int s = m0 & 2047;
        const int u = s & 31;   // u&3 == 0 (s is 4-aligned)
        const int s2 = (s & ~31) | ((u & 12) << 1) | ((u & 16) >> 2);
        u16x4 pk;
#pragma unroll
        for (int j = 0; j < 4; ++j) pk[j] = f2bf(acc[mi][ni][j] + bv);
        *(u16x4*)(out + (((size_t)bb * NH + h) * DKH + dk) * SEQ + s2) = pk;
      }
    }
  }
}

// ---------------------------------------------------------------- output GEMM (bf16 A, f32 out)
// R7's gemm_bt<2,0> verbatim: both operands via global_load_lds, __syncthreads drain.
__global__ __launch_bounds__(256) void gemm_out(const unsigned short* __restrict__ Ah,
                                                const unsigned short* __restrict__ Bw,
                                                const float* __restrict__ bias,
                                                float* __restrict__ out) {
  __shared__ char smem[65536];

  int bid = (int)(blockIdx.y * 8 + blockIdx.x);
  bid = (bid & 7) * 64 + (bid >> 3);
  const int tcol = (bid & 7) * 128;
  const int trow = (bid >> 3) * 128;

  const int lane = threadIdx.x & 63;
  const int w    = threadIdx.x >> 6;
  const int wm = w >> 1, wn = w & 1;
  const int l15 = lane & 15, l4 = lane >> 4;

  const int srow = w * 8 + (lane >> 3);
  const int sc   = ((lane & 7) ^ (lane >> 3)) * 8;

  f32x4 acc[4][4] = {};

  auto stage = [&](int buf, int k0) {
    char* As = smem + buf * 32768;
    char* Bs = As + 16384;
#pragma unroll
    for (int i = 0; i < 4; ++i) {
      gload16(Ah + (size_t)(trow + i * 32 + srow) * DM + k0 + sc, As + i * 4096 + w * 1024);
      gload16(Bw + (size_t)(tcol + i * 32 + srow) * DM + k0 + sc, Bs + i * 4096 + w * 1024);
    }
  };
  auto compute = [&](int buf) {
    char* As = smem + buf * 32768;
    char* Bs = As + 16384;
#pragma unroll
    for (int ks = 0; ks < 2; ++ks) {
      s16x8 af[4], bf[4];
#pragma unroll
      for (int x = 0; x < 4; ++x) {
        const int ra = wm * 64 + x * 16 + l15;
        const int rb = wn * 64 + x * 16 + l15;
        const int kb = ks * 4 + l4;
        af[x] = *(const s16x8*)(As + ra * 128 + ((kb ^ (ra & 7)) << 4));
        bf[x] = *(const s16x8*)(Bs + rb * 128 + ((kb ^ (rb & 7)) << 4));
      }
#pragma unroll
      for (int mi = 0; mi < 4; ++mi)
#pragma unroll
        for (int ni = 0; ni < 4; ++ni)
          acc[mi][ni] = __builtin_amdgcn_mfma_f32_16x16x32_bf16(af[mi], bf[ni], acc[mi][ni], 0, 0, 0);
    }
  };

  stage(0, 0);
  __syncthreads();
  int cur = 0;

  for (int k0 = 0; k0 < DM; k0 += 64) {
    if (k0 + 64 < DM) stage(cur ^ 1, k0 + 64);
    compute(cur);
    __syncthreads();
    cur ^= 1;
  }

#pragma unroll
  for (int ni = 0; ni < 4; ++ni) {
    const int n  = tcol + wn * 64 + ni * 16 + l15;
    const float bv = bias[n];
#pragma unroll
    for (int mi = 0; mi < 4; ++mi) {
      const int m0 = trow + wm * 64 + mi * 16 + l4 * 4;
#pragma unroll
      for (int j = 0; j < 4; ++j)
        out[(size_t)(m0 + j) * DM + n] = acc[mi][ni][j] + bv;
    }
  }
}

// ---------------------------------------------------------------- flash attention (R7 verbatim)
// Swapped QK^T (S^T = mfma(K,Q)), 64 q-rows per wave (ni=4: each K/V LDS b128 read
// feeds 4 MFMAs), NO online max (scores bounded since Q pre-scaled by log2(e)/8),
// l-sum via ones-column MFMA. No cross-lane ops inside the kv loop.
__global__ __launch_bounds__(256, 2) void attn_kernel(const unsigned short* __restrict__ qh,
                                                      const unsigned short* __restrict__ kh,
                                                      const unsigned short* __restrict__ vth,
                                                      unsigned short* __restrict__ ao) {
  __shared__ char smem[32768];   // Ks0 @0, Ks1 @8192, Vs0 @16384, Vs1 @24576

  int bid = (int)blockIdx.x;              // 512 blocks
  bid = (bid & 7) * 64 + (bid >> 3);      // XCD swizzle: 8 heads per XCD -> KV L2-resident
  const int bh = bid >> 3;                // 0..63
  const int q0 = (bid & 7) * 256;         // q tile base

  const int lane = threadIdx.x & 63;
  const int w    = threadIdx.x >> 6;
  const int l15 = lane & 15, l4 = lane >> 4;

  const int qrow = q0 + w * 64;
  const unsigned short* qbase = qh + ((size_t)bh * SEQ + qrow) * DKH;

  s16x8 qf[4][2];
#pragma unroll
  for (int ni = 0; ni < 4; ++ni)
#pragma unroll
    for (int ks = 0; ks < 2; ++ks)
      qf[ni][ks] = *(const s16x8*)(qbase + (ni * 16 + l15) * DKH + ks * 32 + l4 * 8);

  // loop-invariant LDS fragment byte offsets (relative to buffer base)
  int koff[2][4], voff[2][4];
#pragma unroll
  for (int ks = 0; ks < 2; ++ks)
#pragma unroll
    for (int mi = 0; mi < 4; ++mi) {
      const int r = mi * 16 + l15;
      koff[ks][mi] = r * 128 + (((ks * 4 + l4) ^ (r & 7)) << 4);
    }
#pragma unroll
  for (int m = 0; m < 2; ++m)
#pragma unroll
    for (int nd = 0; nd < 4; ++nd) {
      const int r = nd * 16 + l15;
      voff[m][nd] = r * 128 + (((m * 4 + l4) ^ (r & 7)) << 4);
    }

  f32x4 o[4][4] = {};
  f32x4 lsum[4] = {};   // P column-sums via ones-MFMA (valid at lanes l15==0)

  // ones-column B fragment: B[k][n] = (n==0) ? 1 : 0
  s16x8 onesB = (s16x8)0;
  if (l15 == 0) {
#pragma unroll
    for (int j = 0; j < 8; ++j) onesB[j] = (short)0x3F80;
  }

  const unsigned short* kbase = kh  + (size_t)bh * SEQ * DKH;
  const unsigned short* vbase = vth + (size_t)bh * DKH * SEQ;

  auto stageK = [&](int buf, int kv0) {
    char* Ks = smem + buf * 8192;
#pragma unroll
    for (int i = 0; i < 2; ++i) {
      const int row = i * 32 + w * 8 + (lane >> 3);
      const int sc  = ((lane & 7) ^ (row & 7)) << 3;
      gload16(kbase + (size_t)(kv0 + row) * DKH + sc, Ks + i * 4096 + w * 1024);
    }
  };
  auto stageV = [&](int buf, int kv0) {
    char* Vs = smem + 16384 + buf * 8192;
#pragma unroll
    for (int i = 0; i < 2; ++i) {
      const int row = i * 32 + w * 8 + (lane >> 3);   // dk row
      const int sc  = ((lane & 7) ^ (row & 7)) << 3;
      gload16(vbase + (size_t)row * SEQ + kv0 + sc, Vs + i * 4096 + w * 1024);
    }
  };

  f32x4 sa[4][4];

  auto qkt = [&](const char* Ks) {
#pragma unroll
    for (int mi = 0; mi < 4; ++mi)
#pragma unroll
      for (int ni = 0; ni < 4; ++ni) sa[mi][ni] = (f32x4)0.f;
    __builtin_amdgcn_s_setprio(1);
#pragma unroll
    for (int ks = 0; ks < 2; ++ks) {
      s16x8 kf[4];
#pragma unroll
      for (int mi = 0; mi < 4; ++mi) kf[mi] = *(const s16x8*)(Ks + koff[ks][mi]);
#pragma unroll
      for (int mi = 0; mi < 4; ++mi)
#pragma unroll
        for (int ni = 0; ni < 4; ++ni)
          sa[mi][ni] = __builtin_amdgcn_mfma_f32_16x16x32_bf16(kf[mi], qf[ni][ks], sa[mi][ni], 0, 0, 0);
    }
    __builtin_amdgcn_s_setprio(0);
  };

  auto smpv = [&](const char* Vs) {
    // P = exp2(S) in place (Q pre-scaled by log2(e)/8; no max needed, |S| <= ~14.4)
#pragma unroll
    for (int mi = 0; mi < 4; ++mi)
#pragma unroll
      for (int ni = 0; ni < 4; ++ni)
#pragma unroll
        for (int j = 0; j < 4; ++j)
          sa[mi][ni][j] = exp2fast(sa[mi][ni][j]);

    // PV + ones-sum: O[q][dk] += P*V ; lsum += P*ones  (K=32 MFMA, pi-permuted k)
    __builtin_amdgcn_s_setprio(1);
#pragma unroll
    for (int m = 0; m < 2; ++m) {
      s16x8 pa[4];
#pragma unroll
      for (int ni = 0; ni < 4; ++ni) {
        union { unsigned int u[4]; s16x8 v; } pu;
        pu.u[0] = cvtpk(sa[2 * m][ni][0],     sa[2 * m][ni][1]);
        pu.u[1] = cvtpk(sa[2 * m][ni][2],     sa[2 * m][ni][3]);
        pu.u[2] = cvtpk(sa[2 * m + 1][ni][0], sa[2 * m + 1][ni][1]);
        pu.u[3] = cvtpk(sa[2 * m + 1][ni][2], sa[2 * m + 1][ni][3]);
        pa[ni] = pu.v;
      }
#pragma unroll
      for (int ni = 0; ni < 4; ++ni)
        lsum[ni] = __builtin_amdgcn_mfma_f32_16x16x32_bf16(pa[ni], onesB, lsum[ni], 0, 0, 0);
#pragma unroll
      for (int nd = 0; nd < 4; ++nd) {
        const s16x8 vbf = *(const s16x8*)(Vs + voff[m][nd]);
#pragma unroll
        for (int ni = 0; ni < 4; ++ni)
          o[ni][nd] = __builtin_amdgcn_mfma_f32_16x16x32_bf16(pa[ni], vbf, o[ni][nd], 0, 0, 0);
      }
    }
    __builtin_amdgcn_s_setprio(0);
  };

  // ---- 2-phase pipeline: prefetch(t+1) -> compute(t) -> barrier
  stageK(0, 0); stageV(0, 0);
  __syncthreads();

  for (int t = 0; t < 32; t += 2) {
    const int kv0 = t * 64;
    // even tile: compute buf0, prefetch t+1 -> buf1
    stageK(1, kv0 + 64); stageV(1, kv0 + 64);
    qkt(smem);
    smpv(smem + 16384);
    __syncthreads();
    // odd tile: compute buf1, prefetch t+2 -> buf0
    if (t + 2 < 32) { stageK(0, kv0 + 128); stageV(0, kv0 + 128); }
    qkt(smem + 8192);
    smpv(smem + 16384 + 8192);
    __syncthreads();
  }

  // normalize (broadcast lsum from col-0 lanes) + store to (B,S,h*dk)
  const int bb = bh >> 4, h = bh & 15;
#pragma unroll
  for (int ni = 0; ni < 4; ++ni) {
#pragma unroll
    for (int j = 0; j < 4; ++j) {
      const float inv = 1.0f / bperm(lsum[ni][j], lane & 48);
      const int s = qrow + ni * 16 + l4 * 4 + j;
#pragma unroll
      for (int nd = 0; nd < 4; ++nd) {
        const int col = h * 64 + nd * 16 + l15;
        ao[((size_t)bb * SEQ + s) * DM + col] = f2bf(o[ni][nd][j] * inv);
      }
    }
  }
}

// ---------------------------------------------------------------- launch
extern "C" void kernel_launch(void* const* d_in, const int* in_sizes, int n_in,
                              void* d_out, int out_size, void* d_ws, size_t ws_size,
                              hipStream_t stream) {
  const float* Q  = (const float*)d_in[0];
  const float* K  = (const float*)d_in[1];
  const float* V  = (const float*)d_in[2];
  const float* Wq = (const float*)d_in[3];
  const float* bq = (const float*)d_in[4];
  const float* Wk = (const float*)d_in[5];
  const float* bk = (const float*)d_in[6];
  const float* Wv = (const float*)d_in[7];
  const float* bv = (const float*)d_in[8];
  const float* Wo = (const float*)d_in[9];
  const float* bo = (const float*)d_in[10];
  float* out = (float*)d_out;

  char* ws = (char*)d_ws;
  const size_t MB = 1024 * 1024;
  unsigned short* Wqb = (unsigned short*)(ws + 0 * MB);     // 2 MB each
  unsigned short* Wkb = (unsigned short*)(ws + 2 * MB);
  unsigned short* Wvb = (unsigned short*)(ws + 4 * MB);
  unsigned short* Wob = (unsigned short*)(ws + 6 * MB);
  unsigned short* qhd = (unsigned short*)(ws + 8 * MB);     // (B,h,S,dk), pre-scaled by log2e/8
  unsigned short* khd = (unsigned short*)(ws + 24 * MB);    // (B,h,S,dk)
  unsigned short* vtd = (unsigned short*)(ws + 40 * MB);    // (B,h,dk,S') pi-permuted
  unsigned short* aod = (unsigned short*)(ws + 56 * MB);    // (B,S,DM)

  const float QSCALE = 0.18033688011112042f;  // log2(e) / 8 folded into Q projection

  cvt4_kernel<<<dim3(4 * 512), 256, 0, stream>>>(Wq, Wk, Wv, Wo, Wqb, Wkb, Wvb, Wob);

  dim3 gg(DM / 128, MROWS / 128, 3);   // (8, 64, 3) fused QKV, R7 sync
  gemm_qkv<<<gg, 256, 0, stream>>>(Q, K, V, Wqb, Wkb, Wvb, bq, bk, bv,
                                   qhd, khd, vtd, QSCALE);

  attn_kernel<<<dim3(512), 256, 0, stream>>>(qhd, khd, vtd, aod);

  gemm_out<<<dim3(DM / 128, MROWS / 128), 256, 0, stream>>>(aod, Wob, bo, out);
}